// Round 1
// baseline (225.280 us; speedup 1.0000x reference)
//
#include <hip/hip_runtime.h>
#include <math.h>

#define BUF_SIZE 1000
// Mirror the reference's constants exactly (LN2 truncated to 0.693147).
#define TARGET_LOG_MEAN 7.6438561897747395f            // float(np.log2(200.0))
#define TARGET_LOG_STD  (40.0f / (200.0f * 0.693147f)) // 0.288538...

// ---------------------------------------------------------------------------
// Kernel 1: find the last min(1000, n_valid) valid pitches scanning backward,
// compute mean/std of their log2, emit scale/bias for the elementwise pass.
// Single block of 256 threads; expected to touch only ~2 KB of the tail.
// ---------------------------------------------------------------------------
__global__ void stats_kernel(const float* __restrict__ pitch, long long n,
                             float* __restrict__ stats) {
    const int tid = threadIdx.x;
    __shared__ int s_cnt[256];
    __shared__ double s_red[256];

    double sum = 0.0, sumsq = 0.0;
    long long count_so_far = 0;

    const long long nchunks = (n + 1023) >> 10;   // 1024-element chunks
    for (long long c = nchunks - 1; c >= 0; --c) {
        const long long base = (c << 10) + (long long)tid * 4;
        float v[4];
        int valid[4];
        int cnt = 0;
#pragma unroll
        for (int j = 0; j < 4; ++j) {
            const long long idx = base + j;
            const float p = (idx < n) ? pitch[idx] : 0.0f;
            v[j] = p;
            valid[j] = (p > 0.0f) ? 1 : 0;
            cnt += valid[j];
        }

        // Block-wide inclusive scan of per-thread valid counts (Hillis-Steele).
        s_cnt[tid] = cnt;
        __syncthreads();
        for (int off = 1; off < 256; off <<= 1) {
            const int mine = s_cnt[tid];
            const int add = (tid >= off) ? s_cnt[tid - off] : 0;
            __syncthreads();
            s_cnt[tid] = mine + add;
            __syncthreads();
        }
        const int incl = s_cnt[tid];
        const int total = s_cnt[255];
        const int suff_after = total - incl;   // valid elems in higher threads

        // Walk my 4 elements newest-to-oldest, assigning global reverse ranks.
        int r = 0;
#pragma unroll
        for (int j = 3; j >= 0; --j) {
            if (valid[j]) {
                const long long rev = count_so_far + suff_after + r;
                if (rev < BUF_SIZE) {
                    const double lp = (double)__log2f(v[j]);
                    sum += lp;
                    sumsq += lp * lp;
                }
                r++;
            }
        }

        count_so_far += total;
        __syncthreads();                 // s_cnt reused next iteration
        if (count_so_far >= BUF_SIZE) break;   // uniform across block
    }

    // Block reduction of sum and sumsq.
    s_red[tid] = sum;
    __syncthreads();
    for (int off = 128; off > 0; off >>= 1) {
        if (tid < off) s_red[tid] += s_red[tid + off];
        __syncthreads();
    }
    const double tsum = s_red[0];
    __syncthreads();
    s_red[tid] = sumsq;
    __syncthreads();
    for (int off = 128; off > 0; off >>= 1) {
        if (tid < off) s_red[tid] += s_red[tid + off];
        __syncthreads();
    }
    const double tsumsq = s_red[0];

    if (tid == 0) {
        const long long count = (count_so_far < BUF_SIZE) ? count_so_far : BUF_SIZE;
        float mean, stdv;
        if (count == 0) {
            mean = 0.0f;
            stdv = 1.0f;
        } else {
            mean = (float)(tsum / (double)count);
            if (count > 1) {
                double var = (tsumsq - tsum * tsum / (double)count) /
                             (double)(count - 1);
                if (var < 0.0) var = 0.0;
                stdv = (float)sqrt(var);
            } else {
                stdv = 1.0f;
            }
        }
        if (stdv < 1e-7f) stdv = 1e-7f;
        const float scale = TARGET_LOG_STD / stdv;
        const float bias = TARGET_LOG_MEAN - mean * scale;
        stats[0] = scale;
        stats[1] = bias;
    }
}

// ---------------------------------------------------------------------------
// Kernel 2: streaming elementwise transform. float4 loads/stores, grid-stride.
// out = p>0 ? exp2(log2(p)*scale + bias) : 0
// ---------------------------------------------------------------------------
__global__ void apply_kernel(const float4* __restrict__ in4,
                             float4* __restrict__ out4, long long n4,
                             const float* __restrict__ pitch,
                             float* __restrict__ out, long long n,
                             const float* __restrict__ stats) {
    const float scale = stats[0];
    const float bias = stats[1];
    const long long gid = (long long)blockIdx.x * blockDim.x + threadIdx.x;
    const long long stride = (long long)gridDim.x * blockDim.x;

    for (long long k = gid; k < n4; k += stride) {
        const float4 p = in4[k];
        float4 o;
        o.x = (p.x > 0.0f) ? exp2f(fmaf(__log2f(p.x), scale, bias)) : 0.0f;
        o.y = (p.y > 0.0f) ? exp2f(fmaf(__log2f(p.y), scale, bias)) : 0.0f;
        o.z = (p.z > 0.0f) ? exp2f(fmaf(__log2f(p.z), scale, bias)) : 0.0f;
        o.w = (p.w > 0.0f) ? exp2f(fmaf(__log2f(p.w), scale, bias)) : 0.0f;
        out4[k] = o;
    }

    // Scalar tail (n not divisible by 4).
    const long long tail_start = n4 * 4;
    for (long long k = tail_start + gid; k < n; k += stride) {
        const float p = pitch[k];
        out[k] = (p > 0.0f) ? exp2f(fmaf(__log2f(p), scale, bias)) : 0.0f;
    }
}

extern "C" void kernel_launch(void* const* d_in, const int* in_sizes, int n_in,
                              void* d_out, int out_size, void* d_ws, size_t ws_size,
                              hipStream_t stream) {
    const float* pitch = (const float*)d_in[0];
    float* out = (float*)d_out;
    const long long n = (long long)in_sizes[0];
    float* stats = (float*)d_ws;   // [0]=scale, [1]=bias

    stats_kernel<<<1, 256, 0, stream>>>(pitch, n, stats);

    const long long n4 = n / 4;
    int blocks = (int)((n4 + 255) / 256);
    if (blocks > 32768) blocks = 32768;   // grid-stride covers the rest
    if (blocks < 1) blocks = 1;
    apply_kernel<<<blocks, 256, 0, stream>>>((const float4*)pitch, (float4*)out,
                                             n4, pitch, out, n, stats);
}